// Round 1
// 368.349 us; speedup vs baseline: 1.0822x; 1.0822x over previous
//
#include <hip/hip_runtime.h>
#include <cmath>

// Problem constants
#define B_SZ   32
#define LQ     576
#define LV     3024
#define CDIM   384
#define NHEAD  6
#define DHEAD  64
#define NLVL   3
#define NPTS   4
#define NPROJ  216   // 144 offset channels + 72 attn logits
#define NPROJP 256   // padded to 2 x 128 col tiles

typedef short    bx4 __attribute__((ext_vector_type(4)));
typedef short    bx8 __attribute__((ext_vector_type(8)));
typedef float    fx4 __attribute__((ext_vector_type(4)));
typedef _Float16 hx8 __attribute__((ext_vector_type(8)));

__device__ __forceinline__ short f2bf(float f) {
    unsigned u = __builtin_bit_cast(unsigned, f);
    unsigned r = (u + 0x7FFFu + ((u >> 16) & 1u)) >> 16;  // RNE
    return (short)r;
}
__device__ __forceinline__ float bf2f(unsigned short u) {
    return __builtin_bit_cast(float, ((unsigned)u) << 16);
}
__device__ __forceinline__ short f2h(float f) {
    return __builtin_bit_cast(short, (_Float16)f);       // RNE
}

// ---------------------------------------------------------------------------
// W (K x N fp32) -> Wt (N x K bf16)   [384x384]
// ---------------------------------------------------------------------------
__global__ __launch_bounds__(256) void cast_transpose_kernel(
    const float* __restrict__ W, short* __restrict__ Wt, int K, int N)
{
    int idx = blockIdx.x * 256 + threadIdx.x;
    if (idx >= K * N) return;
    int n = idx / K, k = idx - n * K;
    Wt[idx] = f2bf(W[(size_t)k * N + n]);
}

// ---------------------------------------------------------------------------
// Concat f16 transposed weight for off+attn projection, padded to NPROJP.
// ---------------------------------------------------------------------------
__global__ __launch_bounds__(256) void prep_proj_f16_kernel(
    const float* __restrict__ W_off, const float* __restrict__ b_off,
    const float* __restrict__ W_attn, const float* __restrict__ b_attn,
    short* __restrict__ Wf, float* __restrict__ bc)
{
    int idx = blockIdx.x * 256 + threadIdx.x;
    if (idx >= NPROJP * CDIM) return;
    int n = idx / CDIM, k = idx - n * CDIM;
    float w = 0.f;
    if (n < 144)           w = W_off[(size_t)k * 144 + n];
    else if (n < NPROJ)    w = W_attn[(size_t)k * 72 + (n - 144)];
    Wf[idx] = f2h(w);
    if (idx < NPROJP)
        bc[idx] = (idx < 144) ? b_off[idx]
                 : (idx < NPROJ ? b_attn[idx - 144] : 0.f);
}

// ---------------------------------------------------------------------------
// Fused value projection: val[M,384](bf16) = bf16( A[M,384](fp32) @ Wt^T + b )
// BM=128, BN=384 (full N per block -> A read ONCE), BK=64, 512 thr / 8 waves.
// A: fp32 loaded to regs, cast to bf16 in-flight, XOR-swizzled ds_write_b128
//    (octet ^= row&7 at 16-B granularity -- matches the fragment-read swizzle
//    of the proven gemm_dma kernel, so the MFMA read path is unchanged).
// B: global_load_lds DMA, pre-swizzled global source (identical to gemm_dma).
// LDS = 16 KB (As) + 48 KB (Bs) = 64 KB. acc[4][6] per wave (96 VGPRs).
// Replaces cast_bf16 + 3-column-tile gemm_dma: value-path HBM traffic
// 446 MB -> 223 MB, one dispatch fewer. Numerics bitwise-identical.
// ---------------------------------------------------------------------------
__global__ __launch_bounds__(512) void value_gemm_kernel(
    const float* __restrict__ A, const short* __restrict__ Bt,
    const float* __restrict__ bias, short* __restrict__ Cout,
    int M, int K)
{
    constexpr int N = 384;
    __shared__ short As[128 * 64];
    __shared__ short Bs[384 * 64];

    const int tid = threadIdx.x;
    const int m0 = blockIdx.x * 128;

    const int w  = tid >> 6;           // wave 0..7
    const int l  = tid & 63;
    const int wr = (w & 1) * 64;       // wave row offset (2 rows of waves)
    const int wc = (w >> 1) * 96;      // wave col offset (4 cols of waves)
    const int lr = l & 15;
    const int q  = l >> 4;             // lane quad 0..3

    // B DMA staging roles: 8 lanes x 16 B per row
    const int rg  = l >> 3;            // row in 8-row group
    const int cg  = l & 7;             // physical octet this lane fills
    const int csw = cg ^ rg;           // global octet to fetch (XOR swizzle)

    // A reg staging roles: 4 threads per row, 16 fp32 each
    const int am = tid >> 2;           // row 0..127
    const int ak = (tid & 3) << 4;     // k offset 0,16,32,48

    fx4 acc[4][6] = {};

    for (int k0 = 0; k0 < K; k0 += 64) {
        // ---- B: 6 DMA insts per wave (48 rows/wave, 1 KB each) ----
        #pragma unroll
        for (int t = 0; t < 6; ++t) {
            const int rbase = w * 48 + t * 8;          // wave-uniform, mult of 8
            const short* gB = Bt + (size_t)(rbase + rg) * K + k0 + csw * 8;
            __builtin_amdgcn_global_load_lds(
                (const __attribute__((address_space(1))) void*)gB,
                (__attribute__((address_space(3))) void*)&Bs[rbase * 64],
                16, 0, 0);
        }
        // ---- A: load 16 fp32, cast, 2 swizzled ds_write_b128 ----
        {
            const float* gA = A + (size_t)(m0 + am) * K + k0 + ak;
            const float4 v0 = *(const float4*)(gA + 0);
            const float4 v1 = *(const float4*)(gA + 4);
            const float4 v2 = *(const float4*)(gA + 8);
            const float4 v3 = *(const float4*)(gA + 12);
            bx8 s0, s1;
            s0[0] = f2bf(v0.x); s0[1] = f2bf(v0.y); s0[2] = f2bf(v0.z); s0[3] = f2bf(v0.w);
            s0[4] = f2bf(v1.x); s0[5] = f2bf(v1.y); s0[6] = f2bf(v1.z); s0[7] = f2bf(v1.w);
            s1[0] = f2bf(v2.x); s1[1] = f2bf(v2.y); s1[2] = f2bf(v2.z); s1[3] = f2bf(v2.w);
            s1[4] = f2bf(v3.x); s1[5] = f2bf(v3.y); s1[6] = f2bf(v3.z); s1[7] = f2bf(v3.w);
            const int ob = ak >> 3;                   // logical octet base (even)
            const int o0 = (ob + 0) ^ (am & 7);
            const int o1 = (ob + 1) ^ (am & 7);
            *(bx8*)&As[am * 64 + o0 * 8] = s0;
            *(bx8*)&As[am * 64 + o1 * 8] = s1;
        }
        __syncthreads();

        // ---- MFMA: 2 k-steps of 32; octet c = ks*4+q, de-swizzle by lr&7
        #pragma unroll
        for (int ks = 0; ks < 2; ++ks) {
            bx8 af[4], bf[6];
            #pragma unroll
            for (int i = 0; i < 4; ++i)
                af[i] = *(const bx8*)&As[(wr + i * 16 + lr) * 64 +
                                         (((ks * 4 + q) ^ (lr & 7)) << 3)];
            #pragma unroll
            for (int j = 0; j < 6; ++j)
                bf[j] = *(const bx8*)&Bs[(wc + j * 16 + lr) * 64 +
                                         (((ks * 4 + q) ^ (lr & 7)) << 3)];
            #pragma unroll
            for (int i = 0; i < 4; ++i)
                #pragma unroll
                for (int j = 0; j < 6; ++j)
                    acc[i][j] = __builtin_amdgcn_mfma_f32_16x16x32_bf16(
                        af[i], bf[j], acc[i][j], 0, 0, 0);
        }
        __syncthreads();
    }

    // Epilogue: C/D layout col=lane&15, row=(lane>>4)*4+reg
    const int rrow = q * 4;
    #pragma unroll
    for (int j = 0; j < 6; ++j) {
        const int col = wc + j * 16 + lr;
        const float bv = bias[col];
        #pragma unroll
        for (int i = 0; i < 4; ++i) {
            const int row = m0 + wr + i * 16 + rrow;
            #pragma unroll
            for (int r = 0; r < 4; ++r)
                Cout[(size_t)(row + r) * N + col] = f2bf(acc[i][j][r] + bv);
        }
    }
}

// ---------------------------------------------------------------------------
// m97-style DMA GEMM: C[M,384] = A[M,K](bf16) @ Bt[384,K](bf16)^T + bias.
// 128x128 tile, BK=64, 256 threads / 4 waves, acc[4][4].  (out projection)
// ---------------------------------------------------------------------------
template <bool OUT_BF16>
__global__ __launch_bounds__(256) void gemm_dma_kernel(
    const short* __restrict__ A, const short* __restrict__ Bt,
    const float* __restrict__ bias, void* __restrict__ Cout,
    int M, int K)
{
    constexpr int N = 384;
    __shared__ short As[128 * 64];
    __shared__ short Bs[128 * 64];

    const int tid = threadIdx.x;
    const int n0 = blockIdx.x * 128;
    const int m0 = blockIdx.y * 128;

    const int w  = tid >> 6;           // wave 0..3
    const int l  = tid & 63;
    const int wr = (w & 1) * 64;       // wave row offset
    const int wc = (w >> 1) * 64;      // wave col offset
    const int lr = l & 15;
    const int q  = l >> 4;             // lane quad 0..3

    const int rg  = l >> 3;            // row in 8-row group
    const int cg  = l & 7;             // physical octet this lane fills
    const int csw = cg ^ rg;           // global octet to fetch (XOR swizzle)

    fx4 acc[4][4] = {};

    for (int k0 = 0; k0 < K; k0 += 64) {
        #pragma unroll
        for (int t = 0; t < 4; ++t) {
            const int rbase = w * 32 + t * 8;          // wave-uniform
            const short* gA = A + (size_t)(m0 + rbase + rg) * K + k0 + csw * 8;
            __builtin_amdgcn_global_load_lds(
                (const __attribute__((address_space(1))) void*)gA,
                (__attribute__((address_space(3))) void*)&As[rbase * 64],
                16, 0, 0);
            const short* gB = Bt + (size_t)(n0 + rbase + rg) * K + k0 + csw * 8;
            __builtin_amdgcn_global_load_lds(
                (const __attribute__((address_space(1))) void*)gB,
                (__attribute__((address_space(3))) void*)&Bs[rbase * 64],
                16, 0, 0);
        }
        __syncthreads();

        #pragma unroll
        for (int ks = 0; ks < 2; ++ks) {
            bx8 af[4], bf[4];
            #pragma unroll
            for (int i = 0; i < 4; ++i)
                af[i] = *(const bx8*)&As[(wr + i * 16 + lr) * 64 +
                                         (((ks * 4 + q) ^ (lr & 7)) << 3)];
            #pragma unroll
            for (int j = 0; j < 4; ++j)
                bf[j] = *(const bx8*)&Bs[(wc + j * 16 + lr) * 64 +
                                         (((ks * 4 + q) ^ (lr & 7)) << 3)];
            #pragma unroll
            for (int i = 0; i < 4; ++i)
                #pragma unroll
                for (int j = 0; j < 4; ++j)
                    acc[i][j] = __builtin_amdgcn_mfma_f32_16x16x32_bf16(
                        af[i], bf[j], acc[i][j], 0, 0, 0);
        }
        __syncthreads();
    }

    const int rrow = q * 4;
    #pragma unroll
    for (int j = 0; j < 4; ++j) {
        const int col = n0 + wc + j * 16 + lr;
        const float bv = bias[col];
        #pragma unroll
        for (int i = 0; i < 4; ++i) {
            const int row = m0 + wr + i * 16 + rrow;
            #pragma unroll
            for (int r = 0; r < 4; ++r) {
                if (OUT_BF16)
                    ((short*)Cout)[(size_t)(row + r) * N + col] = f2bf(acc[i][j][r] + bv);
                else
                    ((float*)Cout)[(size_t)(row + r) * N + col] = acc[i][j][r] + bv;
            }
        }
    }
}

// ---------------------------------------------------------------------------
// f16 MFMA GEMM for the query projection (fp32 A cast in-flight).
// ---------------------------------------------------------------------------
__global__ __launch_bounds__(256) void gemm_proj_kernel(
    const float* __restrict__ A, const short* __restrict__ Wf,
    const float* __restrict__ bias, float* __restrict__ C,
    int M, int K)
{
    __shared__ short As[128 * 72];
    __shared__ short Bs[128 * 72];

    const int tid = threadIdx.x;
    const int n0 = blockIdx.x * 128;
    const int m0 = blockIdx.y * 128;

    const int w  = tid >> 6;
    const int l  = tid & 63;
    const int wr = (w & 1) * 64;
    const int wc = (w >> 1) * 64;
    const int lr = l & 15;
    const int ko = (l >> 4) * 8;

    fx4 acc[4][4] = {};

    for (int k0 = 0; k0 < K; k0 += 64) {
        #pragma unroll
        for (int r = 0; r < 8; ++r) {
            const int id = tid + r * 256;
            const int m  = id >> 4;
            const int kq = (id & 15) << 2;
            const float4 v = *(const float4*)(A + (size_t)(m0 + m) * K + k0 + kq);
            bx4 s;
            s[0] = f2h(v.x); s[1] = f2h(v.y); s[2] = f2h(v.z); s[3] = f2h(v.w);
            *(bx4*)&As[m * 72 + kq] = s;
        }
        #pragma unroll
        for (int r = 0; r < 4; ++r) {
            const int id = tid + r * 256;
            const int n  = id >> 3;
            const int k8 = (id & 7) << 3;
            *(bx8*)&Bs[n * 72 + k8] = *(const bx8*)(Wf + (size_t)(n0 + n) * K + k0 + k8);
        }
        __syncthreads();

        #pragma unroll
        for (int ks = 0; ks < 2; ++ks) {
            bx8 af[4], bf[4];
            #pragma unroll
            for (int i = 0; i < 4; ++i)
                af[i] = *(const bx8*)&As[(wr + i * 16 + lr) * 72 + ks * 32 + ko];
            #pragma unroll
            for (int j = 0; j < 4; ++j)
                bf[j] = *(const bx8*)&Bs[(wc + j * 16 + lr) * 72 + ks * 32 + ko];
            #pragma unroll
            for (int i = 0; i < 4; ++i)
                #pragma unroll
                for (int j = 0; j < 4; ++j)
                    acc[i][j] = __builtin_amdgcn_mfma_f32_16x16x32_f16(
                        __builtin_bit_cast(hx8, af[i]),
                        __builtin_bit_cast(hx8, bf[j]), acc[i][j], 0, 0, 0);
        }
        __syncthreads();
    }

    const int rrow = (l >> 4) * 4;
    #pragma unroll
    for (int j = 0; j < 4; ++j) {
        const int col = n0 + wc + j * 16 + lr;
        if (col >= NPROJ) continue;
        const float bv = bias[col];
        #pragma unroll
        for (int i = 0; i < 4; ++i) {
            const int row = m0 + wr + i * 16 + rrow;
            #pragma unroll
            for (int r = 0; r < 4; ++r)
                C[(size_t)(row + r) * NPROJ + col] = acc[i][j][r] + bv;
        }
    }
}

// ---------------------------------------------------------------------------
// Reference-point processing (verified round 1)
// ---------------------------------------------------------------------------
__global__ __launch_bounds__(256) void ref_kernel(
    const float* __restrict__ rp, float* __restrict__ refp)
{
    const int b = blockIdx.x;
    const float* r = rp + (size_t)b * LV * 2;
    const int tid = threadIdx.x;

    __shared__ float redx[256], redy[256];
    float sx = 0.f, sy = 0.f;
    for (int i = tid; i < 2304; i += 256) {
        sx += r[2 * i + 0];
        sy += r[2 * i + 1];
    }
    redx[tid] = sx; redy[tid] = sy;
    __syncthreads();
    for (int s = 128; s > 0; s >>= 1) {
        if (tid < s) { redx[tid] += redx[tid + s]; redy[tid] += redy[tid + s]; }
        __syncthreads();
    }
    const float p1x = redx[0] * (1.f / 2304.f);
    const float p1y = redy[0] * (1.f / 2304.f);

    const float* g = r + 2880 * 2;
    for (int q = tid; q < 576; q += 256) {
        const float p2x = r[(2304 + q) * 2 + 0];
        const float p2y = r[(2304 + q) * 2 + 1];
        const int qy = q / 24, qx = q % 24;
        const float syc = fminf(fmaxf(0.5f * qy - 0.25f, 0.f), 11.f);
        const float sxc = fminf(fmaxf(0.5f * qx - 0.25f, 0.f), 11.f);
        int y0 = min((int)syc, 10);
        int x0 = min((int)sxc, 10);
        const float fy = syc - (float)y0, fx = sxc - (float)x0;
        const float v00x = g[(y0 * 12 + x0) * 2 + 0],     v00y = g[(y0 * 12 + x0) * 2 + 1];
        const float v10x = g[(y0 * 12 + x0 + 1) * 2 + 0], v10y = g[(y0 * 12 + x0 + 1) * 2 + 1];
        const float v01x = g[((y0 + 1) * 12 + x0) * 2 + 0],     v01y = g[((y0 + 1) * 12 + x0) * 2 + 1];
        const float v11x = g[((y0 + 1) * 12 + x0 + 1) * 2 + 0], v11y = g[((y0 + 1) * 12 + x0 + 1) * 2 + 1];
        const float p3x = (1.f - fy) * ((1.f - fx) * v00x + fx * v10x)
                        + fy * ((1.f - fx) * v01x + fx * v11x);
        const float p3y = (1.f - fy) * ((1.f - fx) * v00y + fx * v10y)
                        + fy * ((1.f - fx) * v01y + fx * v11y);
        refp[((size_t)b * LQ + q) * 2 + 0] = (p1x + p2x + p3x) * (1.f / 3.f);
        refp[((size_t)b * LQ + q) * 2 + 1] = (p1y + p2y + p3y) * (1.f / 3.f);
    }
}

// ---------------------------------------------------------------------------
// Deformable sampling + softmax + attention accumulate (verified round 6).
// ---------------------------------------------------------------------------
__global__ __launch_bounds__(192) void sample_kernel(
    const unsigned short* __restrict__ val, const float* __restrict__ proj,
    const float* __restrict__ refp, unsigned* __restrict__ mid)
{
    const int i = blockIdx.x;
    const int g = i & 7;
    const int r = i >> 3;
    const int b = g * 4 + (r / LQ);
    const int q = r - (r / LQ) * LQ;
    const int bq = b * LQ + q;
    const int tid = threadIdx.x;

    __shared__ float attn[72];
    __shared__ int   sloc[72][4];
    __shared__ float swt[72][4];

    if (tid < 72) {
        attn[tid] = proj[(size_t)bq * NPROJ + 144 + tid];

        const int h = tid / 12;
        const int rr = tid % 12;
        const int l = rr >> 2;
        const int p = rr & 3;

        const int HL[3] = {48, 24, 12};
        const int ST[3] = {0, 2304, 2880};
        const int Hl = HL[l], Wl = HL[l], st = ST[l];

        const float rx = refp[bq * 2 + 0];
        const float ry = refp[bq * 2 + 1];
        const int oc = ((h * NLVL + l) * NPTS + p) * 2;
        const float cx = proj[(size_t)bq * NPROJ + oc + 0] + rx;
        const float cy = proj[(size_t)bq * NPROJ + oc + 1] + ry;

        const float px = cx * (float)Wl - 0.5f;
        const float py = cy * (float)Hl - 0.5f;
        const float x0f = floorf(px), y0f = floorf(py);
        const float lx = px - x0f, ly = py - y0f;
        const int x0 = (int)x0f, y0 = (int)y0f;

        #pragma unroll
        for (int k = 0; k < 4; ++k) {
            const int dx = k & 1, dy = k >> 1;
            const int xi = x0 + dx, yi = y0 + dy;
            const bool v = (xi >= 0) && (xi < Wl) && (yi >= 0) && (yi < Hl);
            const int xc = min(max(xi, 0), Wl - 1);
            const int yc = min(max(yi, 0), Hl - 1);
            sloc[tid][k] = st + yc * Wl + xc;
            const float wx = dx ? lx : 1.f - lx;
            const float wy = dy ? ly : 1.f - ly;
            swt[tid][k] = v ? wx * wy : 0.f;
        }
    }
    __syncthreads();

    if (tid < NHEAD) {
        float mx = -1e30f;
        #pragma unroll
        for (int j = 0; j < 12; ++j) mx = fmaxf(mx, attn[tid * 12 + j]);
        float s = 0.f;
        #pragma unroll
        for (int j = 0; j < 12; ++j) {
            const float e = expf(attn[tid * 12 + j] - mx);
            attn[tid * 12 + j] = e;
            s += e;
        }
        const float inv = 1.f / s;
        #pragma unroll
        for (int j = 0; j < 12; ++j) attn[tid * 12 + j] *= inv;
    }
    __syncthreads();

    const int h  = tid >> 5;
    const int c2 = (tid & 31) << 1;
    const unsigned* vp = (const unsigned*)(val + (size_t)b * LV * CDIM + h * DHEAD + c2);
    float acc0 = 0.f, acc1 = 0.f;
    #pragma unroll
    for (int s = 0; s < 12; ++s) {
        const int j = h * 12 + s;
        const float a = attn[j];
        float s0 = 0.f, s1 = 0.f;
        #pragma unroll
        for (int k = 0; k < 4; ++k) {
            const unsigned u = vp[(size_t)sloc[j][k] * (CDIM / 2)];
            const float lo = __builtin_bit_cast(float, u << 16);
            const float hi = __builtin_bit_cast(float, u & 0xFFFF0000u);
            s0 += swt[j][k] * lo;
            s1 += swt[j][k] * hi;
        }
        acc0 += a * s0;
        acc1 += a * s1;
    }
    const unsigned lo = (unsigned)(unsigned short)f2bf(acc0);
    const unsigned hi = (unsigned)(unsigned short)f2bf(acc1);
    mid[((size_t)bq * CDIM + h * DHEAD + c2) >> 1] = lo | (hi << 16);
}

// ---------------------------------------------------------------------------
extern "C" void kernel_launch(void* const* d_in, const int* in_sizes, int n_in,
                              void* d_out, int out_size, void* d_ws, size_t ws_size,
                              hipStream_t stream)
{
    (void)in_sizes; (void)n_in; (void)out_size; (void)ws_size;

    const float* query   = (const float*)d_in[0];
    const float* value   = (const float*)d_in[1];
    const float* rp      = (const float*)d_in[2];
    const float* W_value = (const float*)d_in[3];
    const float* b_value = (const float*)d_in[4];
    const float* W_off   = (const float*)d_in[5];
    const float* b_off   = (const float*)d_in[6];
    const float* W_attn  = (const float*)d_in[7];
    const float* b_attn  = (const float*)d_in[8];
    const float* W_out   = (const float*)d_in[9];
    const float* b_out   = (const float*)d_in[10];
    float* out = (float*)d_out;

    // Workspace layout (256-B aligned chunks)
    char* p = (char*)d_ws;
    auto take = [&](size_t bytes) { char* q = p; p += (bytes + 255) & ~(size_t)255; return q; };
    short* val  = (short*)take((size_t)B_SZ * LV * CDIM * 2);     // bf16 val
    short* mid  = (short*)take((size_t)B_SZ * LQ * CDIM * 2);     // bf16 mid
    short* Wtv  = (short*)take((size_t)CDIM * CDIM * 2);          // bf16 W_value^T
    short* Wto  = (short*)take((size_t)CDIM * CDIM * 2);          // bf16 W_out^T
    short* Wf   = (short*)take((size_t)NPROJP * CDIM * 2);        // f16 proj W^T
    float* proj = (float*)take((size_t)B_SZ * LQ * NPROJ * 4);
    float* refp = (float*)take((size_t)B_SZ * LQ * 2 * 4);
    float* bc   = (float*)take((size_t)NPROJP * 4);

    const int Mv = B_SZ * LV;   // 96768
    const int Mq = B_SZ * LQ;   // 18432

    // 0) weight prep (tiny)
    cast_transpose_kernel<<<(CDIM * CDIM + 255) / 256, 256, 0, stream>>>(
        W_value, Wtv, CDIM, CDIM);
    cast_transpose_kernel<<<(CDIM * CDIM + 255) / 256, 256, 0, stream>>>(
        W_out, Wto, CDIM, CDIM);
    prep_proj_f16_kernel<<<(NPROJP * CDIM + 255) / 256, 256, 0, stream>>>(
        W_off, b_off, W_attn, b_attn, Wf, bc);

    // 1) val = bf16(value @ W_value + b_value)  (fused cast + full-N GEMM)
    value_gemm_kernel<<<Mv / 128, 512, 0, stream>>>(
        value, Wtv, b_value, val, Mv, CDIM);
    // 2) proj = query @ [W_off|W_attn] + bias   (f16 MFMA)
    gemm_proj_kernel<<<dim3(2, Mq / 128), 256, 0, stream>>>(
        query, Wf, bc, proj, Mq, CDIM);
    // 3) reference points
    ref_kernel<<<B_SZ, 256, 0, stream>>>(rp, refp);
    // 4) softmax + deformable sampling (XCD-swizzled)
    sample_kernel<<<Mq, 192, 0, stream>>>(
        (const unsigned short*)val, proj, refp, (unsigned*)mid);
    // 5) out = mid @ W_out + b_out              (DMA-staged MFMA)
    gemm_dma_kernel<false><<<dim3(3, Mq / 128), 256, 0, stream>>>(
        mid, Wto, b_out, out, Mq, CDIM);
}